// Round 25
// baseline (38.112 us; speedup 1.0000x reference)
//
#include <hip/hip_runtime.h>
#include <math.h>

#define BB 4
#define LL 256
#define TT 256
#define DD 512

// e^{2x} = exp2(x * 2/ln2)
#define EXP2K 2.885390081777927f

using short8  = __attribute__((ext_vector_type(8))) short;
using f32x4   = __attribute__((ext_vector_type(4))) float;

__device__ __forceinline__ unsigned cvt2bf(float a, float b) {
  unsigned r;
  asm("v_cvt_pk_bf16_f32 %0, %1, %2" : "=v"(r) : "v"(a), "v"(b));
  return r;  // lo = bf16(a), hi = bf16(b)
}

// ---------------------------------------------------------------------------
// Kernel 1: combined projection GEMM via bf16 MFMA, fp32 accumulate, with
// register-prefetch staging (R22-proven, unchanged).
// Rows 0..1023:   E1  = exp(2*(x@W1^T+b1))   f32 row-major [B*L, D]
// Rows 1024..2047: E2c = exp(2*(mem@W2^T+b2)) f32 CHUNKED [d>>2][b*T+t][d&3]
// ---------------------------------------------------------------------------
__global__ __launch_bounds__(256) void proj_gemm(
    const float* __restrict__ x, const float* __restrict__ mem,
    const float* __restrict__ W1, const float* __restrict__ b1,
    const float* __restrict__ W2, const float* __restrict__ b2,
    float* __restrict__ E1, float* __restrict__ E2c)
{
  __shared__ __align__(16) char Abuf[32 * 144];   // 32 rows x 64 bf16 (+pad)
  __shared__ __align__(16) char Bbuf[64 * 144];   // 64 cols x 64 bf16 (+pad)

  const int tid = threadIdx.x;
  const int m0 = blockIdx.x * 32;      // 0..2047 in steps of 32
  const int n0 = blockIdx.y * 64;      // 0..511  in steps of 64
  const bool second = (m0 >= BB * LL);

  const float* A    = second ? mem + (size_t)(m0 - BB * LL) * DD
                             : x   + (size_t)m0 * DD;
  const float* W    = second ? W2 : W1;
  const float* bias = second ? b2 : b1;

  const int srow = tid >> 4;           // 0..15 staging row
  const int kq   = (tid & 15) * 4;     // k quad within 64

  const int lane = tid & 63;
  const int wid  = tid >> 6;
  const int r0   = (wid & 1) * 16;
  const int n0w  = (wid >> 1) * 32;
  const int lr   = lane & 15;
  const int lg   = lane >> 4;

  const int aoff  = (r0 + lr) * 144 + lg * 16;
  const int boff0 = (n0w + lr) * 144 + lg * 16;
  const int boff1 = (n0w + 16 + lr) * 144 + lg * 16;

  f32x4 acc0 = {0.f, 0.f, 0.f, 0.f};
  f32x4 acc1 = {0.f, 0.f, 0.f, 0.f};

  const float* Ap = A + (size_t)srow * DD + kq;
  const float* Wp = W + (size_t)(n0 + srow) * DD + kq;

  // preload tile kc=0 into registers
  float4 rA0 = *(const float4*)(Ap);
  float4 rA1 = *(const float4*)(Ap + (size_t)16 * DD);
  float4 rB0 = *(const float4*)(Wp);
  float4 rB1 = *(const float4*)(Wp + (size_t)16 * DD);
  float4 rB2 = *(const float4*)(Wp + (size_t)32 * DD);
  float4 rB3 = *(const float4*)(Wp + (size_t)48 * DD);

  for (int kc = 0; kc < DD; kc += 64) {
    __syncthreads();   // previous iteration's frag reads done
    {
      uint2 u0 = {cvt2bf(rA0.x, rA0.y), cvt2bf(rA0.z, rA0.w)};
      *(uint2*)(Abuf + srow * 144 + kq * 2) = u0;
      uint2 u1 = {cvt2bf(rA1.x, rA1.y), cvt2bf(rA1.z, rA1.w)};
      *(uint2*)(Abuf + (srow + 16) * 144 + kq * 2) = u1;
      uint2 v0 = {cvt2bf(rB0.x, rB0.y), cvt2bf(rB0.z, rB0.w)};
      *(uint2*)(Bbuf + srow * 144 + kq * 2) = v0;
      uint2 v1 = {cvt2bf(rB1.x, rB1.y), cvt2bf(rB1.z, rB1.w)};
      *(uint2*)(Bbuf + (srow + 16) * 144 + kq * 2) = v1;
      uint2 v2 = {cvt2bf(rB2.x, rB2.y), cvt2bf(rB2.z, rB2.w)};
      *(uint2*)(Bbuf + (srow + 32) * 144 + kq * 2) = v2;
      uint2 v3 = {cvt2bf(rB3.x, rB3.y), cvt2bf(rB3.z, rB3.w)};
      *(uint2*)(Bbuf + (srow + 48) * 144 + kq * 2) = v3;
    }
    __syncthreads();   // LDS tile ready
    if (kc + 64 < DD) {   // prefetch next tile; retires under MFMA
      const float* An = Ap + kc + 64;
      const float* Wn = Wp + kc + 64;
      rA0 = *(const float4*)(An);
      rA1 = *(const float4*)(An + (size_t)16 * DD);
      rB0 = *(const float4*)(Wn);
      rB1 = *(const float4*)(Wn + (size_t)16 * DD);
      rB2 = *(const float4*)(Wn + (size_t)32 * DD);
      rB3 = *(const float4*)(Wn + (size_t)48 * DD);
    }
#pragma unroll
    for (int ks = 0; ks < 2; ++ks) {
      short8 af  = *(const short8*)(Abuf + aoff  + ks * 64);
      short8 bf0 = *(const short8*)(Bbuf + boff0 + ks * 64);
      short8 bf1 = *(const short8*)(Bbuf + boff1 + ks * 64);
      acc0 = __builtin_amdgcn_mfma_f32_16x16x32_bf16(af, bf0, acc0, 0, 0, 0);
      acc1 = __builtin_amdgcn_mfma_f32_16x16x32_bf16(af, bf1, acc1, 0, 0, 0);
    }
  }

  // epilogue: C layout col=lane&15, row=(lane>>4)*4+i
#pragma unroll
  for (int nf = 0; nf < 2; ++nf) {
    const f32x4 a = nf ? acc1 : acc0;
    const int col = n0 + n0w + nf * 16 + lr;
    const float bv = bias[col];
#pragma unroll
    for (int i = 0; i < 4; ++i) {
      const int mrow = m0 + r0 + lg * 4 + i;
      const float val = exp2f((a[i] + bv) * EXP2K);
      if (!second) {
        E1[(size_t)mrow * DD + col] = val;
      } else {
        const int m2 = mrow - BB * LL;
        E2c[((size_t)(col >> 2) * (BB * TT) + m2) * 4 + (col & 3)] = val;
      }
    }
  }
}

// ---------------------------------------------------------------------------
// Kernel 2: score + softmax — R24 structure + MANUAL DOUBLE-BUFFERED vv
// PIPELINE (the R22 register-prefetch lever applied to score). Per tile:
// second-half loads (j=8..15) issue at loop top; first half computes from
// held registers c0..c7; NEXT tile's first half issues into c0..c7 between
// the halves; second half computes from n0..n7. Every vv load gets a full
// compute-half of latency cover, including across tile boundaries.
// VGPR ~90 <= 128 -> 2 blocks/CU (4 waves/SIMD) preserved.
// Everything else identical: zero barriers in tile loop, one cross-octant
// reduce, S fully initialized, normalized f32 P store, XCD decode.
// ---------------------------------------------------------------------------
#define ACC1Q(vv, J)                                                          \
  {                                                                           \
    const float4 q0 = q0p[J];                                                 \
    const float4 w  = wp[J];                                                  \
    a0 = fmaf(w.x, __builtin_amdgcn_rcpf(fmaf(q0.x, vv.x, 1.0f)), a0);        \
    a1 = fmaf(w.y, __builtin_amdgcn_rcpf(fmaf(q0.y, vv.y, 1.0f)), a1);        \
    a2 = fmaf(w.z, __builtin_amdgcn_rcpf(fmaf(q0.z, vv.z, 1.0f)), a2);        \
    a3 = fmaf(w.w, __builtin_amdgcn_rcpf(fmaf(q0.w, vv.w, 1.0f)), a3);        \
  }
#define ACC2Q(vv, J)                                                          \
  {                                                                           \
    const float4 q0 = q0p[J];                                                 \
    const float4 q1 = q1p[J];                                                 \
    const float4 w  = wp[J];                                                  \
    a0 = fmaf(w.x, __builtin_amdgcn_rcpf(fmaf(q0.x, vv.x, 1.0f)), a0);        \
    a1 = fmaf(w.y, __builtin_amdgcn_rcpf(fmaf(q0.y, vv.y, 1.0f)), a1);        \
    a2 = fmaf(w.z, __builtin_amdgcn_rcpf(fmaf(q0.z, vv.z, 1.0f)), a2);        \
    a3 = fmaf(w.w, __builtin_amdgcn_rcpf(fmaf(q0.w, vv.w, 1.0f)), a3);        \
    b0 = fmaf(w.x, __builtin_amdgcn_rcpf(fmaf(q1.x, vv.x, 1.0f)), b0);        \
    b1 = fmaf(w.y, __builtin_amdgcn_rcpf(fmaf(q1.y, vv.y, 1.0f)), b1);        \
    b2 = fmaf(w.z, __builtin_amdgcn_rcpf(fmaf(q1.z, vv.z, 1.0f)), b2);        \
    b3 = fmaf(w.w, __builtin_amdgcn_rcpf(fmaf(q1.w, vv.w, 1.0f)), b3);        \
  }

__global__ __launch_bounds__(512) void score_softmax(
    const float* __restrict__ E1, const float* __restrict__ E2c,
    const float* __restrict__ wt, const int* __restrict__ mask,
    float* __restrict__ Pg)
{
  __shared__ float prt[2][4][8][64];       // (row, tile, d-octant, t-lane) 16KB
  __shared__ float S[2][TT];               // raw scores per row             2KB

  const int tid = threadIdx.x;             // 0..511
  const int tl  = tid & 63;
  const int wv  = tid >> 6;                // 0..7
  const int dq  = __builtin_amdgcn_readfirstlane(wv);  // wave-uniform octant

  // XCD-affinity decode (bid%8 = XCD round-robin)
  const int bid = blockIdx.x;              // 0..511
  const int k   = bid & 7;
  const int b   = k >> 1;
  const int lp  = (bid >> 3) + ((k & 1) << 6);   // 0..127

  const int r0 = lp;
  const int r1 = 255 - lp;
  const int tc0 = r0 >> 6;          // 0 or 1
  const int tc1 = r1 >> 6;          // 3 or 2  (tc1 == 3 - tc0)

  const size_t strE2 = (size_t)(BB * TT);  // float4 stride per d4 plane
  const float4* wp  = (const float4*)wt + dq * 16;
  const float4* q0p = (const float4*)(E1 + (size_t)(b * LL + r0) * DD) + dq * 16;
  const float4* q1p = (const float4*)(E1 + (size_t)(b * LL + r1) * DD) + dq * 16;
  const float4* vb  = (const float4*)E2c + (size_t)(dq * 16) * strE2 + b * TT + tl;

  // preload first half (j=0..7) of tile tc0
  float4 c0v, c1v, c2v, c3v, c4v, c5v, c6v, c7v;
  {
    const int off = tc0 * 64;
    c0v = vb[(size_t)0 * strE2 + off];
    c1v = vb[(size_t)1 * strE2 + off];
    c2v = vb[(size_t)2 * strE2 + off];
    c3v = vb[(size_t)3 * strE2 + off];
    c4v = vb[(size_t)4 * strE2 + off];
    c5v = vb[(size_t)5 * strE2 + off];
    c6v = vb[(size_t)6 * strE2 + off];
    c7v = vb[(size_t)7 * strE2 + off];
  }

  // ---- score phase: tile loop, NO barriers, double-buffered vv ----
  for (int tc = tc0; tc < 4; ++tc) {
    const bool shr = (tc >= tc1);          // block-uniform
    const int off = tc * 64;

    // issue second-half loads (j=8..15) — in flight during first-half compute
    float4 n0v = vb[(size_t) 8 * strE2 + off];
    float4 n1v = vb[(size_t) 9 * strE2 + off];
    float4 n2v = vb[(size_t)10 * strE2 + off];
    float4 n3v = vb[(size_t)11 * strE2 + off];
    float4 n4v = vb[(size_t)12 * strE2 + off];
    float4 n5v = vb[(size_t)13 * strE2 + off];
    float4 n6v = vb[(size_t)14 * strE2 + off];
    float4 n7v = vb[(size_t)15 * strE2 + off];

    float a0 = 0.f, a1 = 0.f, a2 = 0.f, a3 = 0.f;
    float b0 = 0.f, b1 = 0.f, b2 = 0.f, b3 = 0.f;

    // compute first half from held registers
    if (shr) {
      ACC2Q(c0v, 0) ACC2Q(c1v, 1) ACC2Q(c2v, 2) ACC2Q(c3v, 3)
      ACC2Q(c4v, 4) ACC2Q(c5v, 5) ACC2Q(c6v, 6) ACC2Q(c7v, 7)
    } else {
      ACC1Q(c0v, 0) ACC1Q(c1v, 1) ACC1Q(c2v, 2) ACC1Q(c3v, 3)
      ACC1Q(c4v, 4) ACC1Q(c5v, 5) ACC1Q(c6v, 6) ACC1Q(c7v, 7)
    }

    // issue NEXT tile's first-half loads — in flight during second-half compute
    if (tc < 3) {
      const int offn = off + 64;
      c0v = vb[(size_t)0 * strE2 + offn];
      c1v = vb[(size_t)1 * strE2 + offn];
      c2v = vb[(size_t)2 * strE2 + offn];
      c3v = vb[(size_t)3 * strE2 + offn];
      c4v = vb[(size_t)4 * strE2 + offn];
      c5v = vb[(size_t)5 * strE2 + offn];
      c6v = vb[(size_t)6 * strE2 + offn];
      c7v = vb[(size_t)7 * strE2 + offn];
    }

    // compute second half
    if (shr) {
      ACC2Q(n0v,  8) ACC2Q(n1v,  9) ACC2Q(n2v, 10) ACC2Q(n3v, 11)
      ACC2Q(n4v, 12) ACC2Q(n5v, 13) ACC2Q(n6v, 14) ACC2Q(n7v, 15)
    } else {
      ACC1Q(n0v,  8) ACC1Q(n1v,  9) ACC1Q(n2v, 10) ACC1Q(n3v, 11)
      ACC1Q(n4v, 12) ACC1Q(n5v, 13) ACC1Q(n6v, 14) ACC1Q(n7v, 15)
    }

    prt[0][tc][dq][tl] = (a0 + a1) + (a2 + a3);
    if (shr) prt[1][tc][dq][tl] = (b0 + b1) + (b2 + b3);
  }
  __syncthreads();

  // ---- single cross-octant reduce: 512 threads; S fully initialized ----
  {
    const int rr = tid >> 8;           // 0..1
    const int t  = tid & 255;
    const int lo = (rr ? tc1 : tc0) << 6;
    if (t >= lo) {
      const float* pp = &prt[rr][t >> 6][0][t & 63];
      float s = 0.f;
#pragma unroll
      for (int oc = 0; oc < 8; ++oc) s += pp[oc * 64];
      S[rr][t] = s;
    } else {
      S[rr][t] = 5e29f;               // -2*S = -1e30 (masked sentinel)
    }
  }
  __syncthreads();

  // ---- softmax + normalized f32 P store: wave 0 -> r0, wave 1 -> r1 ----
  if (wv < 2) {
    const int row = wv ? r1 : r0;
    const int tb = tl * 4;
    float4 h = *(const float4*)(&S[wv][tb]);
    const int4 mk = *(const int4*)(mask + b * TT + tb);
    float v0 = (tb + 0 >= row && mk.x != 0) ? -2.0f * h.x : -1e30f;
    float v1 = (tb + 1 >= row && mk.y != 0) ? -2.0f * h.y : -1e30f;
    float v2 = (tb + 2 >= row && mk.z != 0) ? -2.0f * h.z : -1e30f;
    float v3 = (tb + 3 >= row && mk.w != 0) ? -2.0f * h.w : -1e30f;
    float mx = fmaxf(fmaxf(v0, v1), fmaxf(v2, v3));
#pragma unroll
    for (int o = 1; o < 64; o <<= 1) mx = fmaxf(mx, __shfl_xor(mx, o));
    float e0 = __expf(v0 - mx), e1 = __expf(v1 - mx),
          e2 = __expf(v2 - mx), e3 = __expf(v3 - mx);
    float sm = (e0 + e1) + (e2 + e3);
#pragma unroll
    for (int o = 1; o < 64; o <<= 1) sm += __shfl_xor(sm, o);
    const float rinv = 1.0f / sm;            // butterfly: all lanes have sum
    float4 pv = {e0 * rinv, e1 * rinv, e2 * rinv, e3 * rinv};
    *(float4*)(Pg + (size_t)(b * LL + row) * TT + tb) = pv;
  }
}

// ---------------------------------------------------------------------------
// Kernel 3: PV as bf16-MFMA GEMM with register-prefetch staging (R22-proven,
// unchanged). out[b] = P[b] (MxK) x mem[b] (KxN), 32x64 tile, BK=64,
// 256 threads. A = Pg (f32) cvt'd to bf16 at LDS-write. B = mem staged with
// in-LDS transpose. fp32 accumulate, direct f32 store.
// ---------------------------------------------------------------------------
__global__ __launch_bounds__(256) void pv_gemm(
    const float* __restrict__ Pg, const float* __restrict__ mem,
    float* __restrict__ out)
{
  __shared__ __align__(16) char Abuf[32 * 144];   // 32 rows x 64 bf16 (+pad)
  __shared__ __align__(16) char Bbuf[64 * 144];   // 64 n-cols x 64 k bf16 (+pad)

  const int tid = threadIdx.x;
  const int bid = blockIdx.x;          // 0..255
  const int b   = bid >> 6;
  const int rem = bid & 63;
  const int m0  = (rem >> 3) * 32;
  const int n0  = (rem & 7) * 64;

  const int arow = tid >> 3;           // 0..31
  const int k8   = (tid & 7) * 8;      // 0..56
  const int nq   = tid & 15;           // n quad 0..15
  const int kp0  = tid >> 4;           // k-pair 0..15 (and +16)

  const int lane = tid & 63;
  const int wid  = tid >> 6;
  const int r0   = (wid & 1) * 16;
  const int n0w  = (wid >> 1) * 32;
  const int lr   = lane & 15;
  const int lg   = lane >> 4;

  const int aoff  = (r0 + lr) * 144 + lg * 16;
  const int boff0 = (n0w + lr) * 144 + lg * 16;
  const int boff1 = (n0w + 16 + lr) * 144 + lg * 16;

  f32x4 acc0 = {0.f, 0.f, 0.f, 0.f};
  f32x4 acc1 = {0.f, 0.f, 0.f, 0.f};

  const float* Pb = Pg + (size_t)(b * LL) * TT;
  const float* Mb = mem + (size_t)(b * TT) * DD;
  const float* Pa = Pb + (size_t)(m0 + arow) * TT + k8;
  const float* Mq = Mb + n0 + nq * 4;

  // preload tile kc=0
  float4 pa1 = *(const float4*)(Pa);
  float4 pa2 = *(const float4*)(Pa + 4);
  float4 fa0 = *(const float4*)(Mq + (size_t)(kp0 * 2) * DD);
  float4 fb0 = *(const float4*)(Mq + (size_t)(kp0 * 2 + 1) * DD);
  float4 fa1 = *(const float4*)(Mq + (size_t)((kp0 + 16) * 2) * DD);
  float4 fb1 = *(const float4*)(Mq + (size_t)((kp0 + 16) * 2 + 1) * DD);

  for (int kc = 0; kc < TT; kc += 64) {
    __syncthreads();
    // A: P tile — cvt at write time
    {
      uint4 u = {cvt2bf(pa1.x, pa1.y), cvt2bf(pa1.z, pa1.w),
                 cvt2bf(pa2.x, pa2.y), cvt2bf(pa2.z, pa2.w)};
      *(uint4*)(Abuf + arow * 144 + k8 * 2) = u;
    }
    // B: mem tile transpose-write
    {
      *(unsigned*)(Bbuf + (nq * 4 + 0) * 144 + kp0 * 4) = cvt2bf(fa0.x, fb0.x);
      *(unsigned*)(Bbuf + (nq * 4 + 1) * 144 + kp0 * 4) = cvt2bf(fa0.y, fb0.y);
      *(unsigned*)(Bbuf + (nq * 4 + 2) * 144 + kp0 * 4) = cvt2bf(fa0.z, fb0.z);
      *(unsigned*)(Bbuf + (nq * 4 + 3) * 144 + kp0 * 4) = cvt2bf(fa0.w, fb0.w);
      const int kp1 = kp0 + 16;
      *(unsigned*)(Bbuf + (nq * 4 + 0) * 144 + kp1 * 4) = cvt2bf(fa1.x, fb1.x);
      *(unsigned*)(Bbuf + (nq * 4 + 1) * 144 + kp1 * 4) = cvt2bf(fa1.y, fb1.y);
      *(unsigned*)(Bbuf + (nq * 4 + 2) * 144 + kp1 * 4) = cvt2bf(fa1.z, fb1.z);
      *(unsigned*)(Bbuf + (nq * 4 + 3) * 144 + kp1 * 4) = cvt2bf(fa1.w, fb1.w);
    }
    __syncthreads();
    if (kc + 64 < TT) {   // prefetch next tile; retires under MFMA
      const int kn = kc + 64;
      pa1 = *(const float4*)(Pa + kn);
      pa2 = *(const float4*)(Pa + kn + 4);
      fa0 = *(const float4*)(Mq + (size_t)(kn + kp0 * 2) * DD);
      fb0 = *(const float4*)(Mq + (size_t)(kn + kp0 * 2 + 1) * DD);
      fa1 = *(const float4*)(Mq + (size_t)(kn + (kp0 + 16) * 2) * DD);
      fb1 = *(const float4*)(Mq + (size_t)(kn + (kp0 + 16) * 2 + 1) * DD);
    }
#pragma unroll
    for (int ks = 0; ks < 2; ++ks) {
      short8 af  = *(const short8*)(Abuf + aoff  + ks * 64);
      short8 bf0 = *(const short8*)(Bbuf + boff0 + ks * 64);
      short8 bf1 = *(const short8*)(Bbuf + boff1 + ks * 64);
      acc0 = __builtin_amdgcn_mfma_f32_16x16x32_bf16(af, bf0, acc0, 0, 0, 0);
      acc1 = __builtin_amdgcn_mfma_f32_16x16x32_bf16(af, bf1, acc1, 0, 0, 0);
    }
  }

  // epilogue: direct f32 store (no bias/activation)
#pragma unroll
  for (int nf = 0; nf < 2; ++nf) {
    const f32x4 a = nf ? acc1 : acc0;
    const int col = n0 + n0w + nf * 16 + lr;
#pragma unroll
    for (int i = 0; i < 4; ++i) {
      const int mrow = m0 + r0 + lg * 4 + i;
      out[(size_t)(b * LL + mrow) * DD + col] = a[i];
    }
  }
}

extern "C" void kernel_launch(void* const* d_in, const int* in_sizes, int n_in,
                              void* d_out, int out_size, void* d_ws, size_t ws_size,
                              hipStream_t stream) {
  const float* x   = (const float*)d_in[0];
  const float* mem = (const float*)d_in[1];
  const float* W1  = (const float*)d_in[2];
  const float* b1  = (const float*)d_in[3];
  const float* W2  = (const float*)d_in[4];
  const float* b2  = (const float*)d_in[5];
  const float* wt  = (const float*)d_in[6];
  const int* mask  = (const int*)d_in[8];
  float* outp = (float*)d_out;

  float* E1  = (float*)d_ws;                     // [B*L, D]      2 MB f32
  float* E2c = E1 + (size_t)BB * LL * DD;        // chunked       2 MB f32
  float* Pg  = E2c + (size_t)BB * TT * DD;       // [B][L][T]     1 MB f32 (5 MB)

  proj_gemm<<<dim3((BB * LL + BB * TT) / 32, DD / 64), 256, 0, stream>>>(
      x, mem, W1, b1, W2, b2, E1, E2c);
  score_softmax<<<512, 512, 0, stream>>>(E1, E2c, wt, mask, Pg);
  pv_gemm<<<256, 256, 0, stream>>>(Pg, mem, outp);
}

// Round 26
// 32.550 us; speedup vs baseline: 1.1709x; 1.1709x over previous
//
#include <hip/hip_runtime.h>
#include <math.h>

#define BB 4
#define LL 256
#define TT 256
#define DD 512

// e^{2x} = exp2(x * 2/ln2)
#define EXP2K 2.885390081777927f

using short8  = __attribute__((ext_vector_type(8))) short;
using f32x4   = __attribute__((ext_vector_type(4))) float;

__device__ __forceinline__ unsigned cvt2bf(float a, float b) {
  unsigned r;
  asm("v_cvt_pk_bf16_f32 %0, %1, %2" : "=v"(r) : "v"(a), "v"(b));
  return r;  // lo = bf16(a), hi = bf16(b)
}

// ---------------------------------------------------------------------------
// Kernel 1: combined projection GEMM via bf16 MFMA, fp32 accumulate, with
// register-prefetch staging (R22-proven, unchanged).
// Rows 0..1023:   E1  = exp(2*(x@W1^T+b1))   f32 row-major [B*L, D]
// Rows 1024..2047: E2c = exp(2*(mem@W2^T+b2)) f32 CHUNKED [d>>2][b*T+t][d&3]
// ---------------------------------------------------------------------------
__global__ __launch_bounds__(256) void proj_gemm(
    const float* __restrict__ x, const float* __restrict__ mem,
    const float* __restrict__ W1, const float* __restrict__ b1,
    const float* __restrict__ W2, const float* __restrict__ b2,
    float* __restrict__ E1, float* __restrict__ E2c)
{
  __shared__ __align__(16) char Abuf[32 * 144];   // 32 rows x 64 bf16 (+pad)
  __shared__ __align__(16) char Bbuf[64 * 144];   // 64 cols x 64 bf16 (+pad)

  const int tid = threadIdx.x;
  const int m0 = blockIdx.x * 32;      // 0..2047 in steps of 32
  const int n0 = blockIdx.y * 64;      // 0..511  in steps of 64
  const bool second = (m0 >= BB * LL);

  const float* A    = second ? mem + (size_t)(m0 - BB * LL) * DD
                             : x   + (size_t)m0 * DD;
  const float* W    = second ? W2 : W1;
  const float* bias = second ? b2 : b1;

  const int srow = tid >> 4;           // 0..15 staging row
  const int kq   = (tid & 15) * 4;     // k quad within 64

  const int lane = tid & 63;
  const int wid  = tid >> 6;
  const int r0   = (wid & 1) * 16;
  const int n0w  = (wid >> 1) * 32;
  const int lr   = lane & 15;
  const int lg   = lane >> 4;

  const int aoff  = (r0 + lr) * 144 + lg * 16;
  const int boff0 = (n0w + lr) * 144 + lg * 16;
  const int boff1 = (n0w + 16 + lr) * 144 + lg * 16;

  f32x4 acc0 = {0.f, 0.f, 0.f, 0.f};
  f32x4 acc1 = {0.f, 0.f, 0.f, 0.f};

  const float* Ap = A + (size_t)srow * DD + kq;
  const float* Wp = W + (size_t)(n0 + srow) * DD + kq;

  // preload tile kc=0 into registers
  float4 rA0 = *(const float4*)(Ap);
  float4 rA1 = *(const float4*)(Ap + (size_t)16 * DD);
  float4 rB0 = *(const float4*)(Wp);
  float4 rB1 = *(const float4*)(Wp + (size_t)16 * DD);
  float4 rB2 = *(const float4*)(Wp + (size_t)32 * DD);
  float4 rB3 = *(const float4*)(Wp + (size_t)48 * DD);

  for (int kc = 0; kc < DD; kc += 64) {
    __syncthreads();   // previous iteration's frag reads done
    {
      uint2 u0 = {cvt2bf(rA0.x, rA0.y), cvt2bf(rA0.z, rA0.w)};
      *(uint2*)(Abuf + srow * 144 + kq * 2) = u0;
      uint2 u1 = {cvt2bf(rA1.x, rA1.y), cvt2bf(rA1.z, rA1.w)};
      *(uint2*)(Abuf + (srow + 16) * 144 + kq * 2) = u1;
      uint2 v0 = {cvt2bf(rB0.x, rB0.y), cvt2bf(rB0.z, rB0.w)};
      *(uint2*)(Bbuf + srow * 144 + kq * 2) = v0;
      uint2 v1 = {cvt2bf(rB1.x, rB1.y), cvt2bf(rB1.z, rB1.w)};
      *(uint2*)(Bbuf + (srow + 16) * 144 + kq * 2) = v1;
      uint2 v2 = {cvt2bf(rB2.x, rB2.y), cvt2bf(rB2.z, rB2.w)};
      *(uint2*)(Bbuf + (srow + 32) * 144 + kq * 2) = v2;
      uint2 v3 = {cvt2bf(rB3.x, rB3.y), cvt2bf(rB3.z, rB3.w)};
      *(uint2*)(Bbuf + (srow + 48) * 144 + kq * 2) = v3;
    }
    __syncthreads();   // LDS tile ready
    if (kc + 64 < DD) {   // prefetch next tile; retires under MFMA
      const float* An = Ap + kc + 64;
      const float* Wn = Wp + kc + 64;
      rA0 = *(const float4*)(An);
      rA1 = *(const float4*)(An + (size_t)16 * DD);
      rB0 = *(const float4*)(Wn);
      rB1 = *(const float4*)(Wn + (size_t)16 * DD);
      rB2 = *(const float4*)(Wn + (size_t)32 * DD);
      rB3 = *(const float4*)(Wn + (size_t)48 * DD);
    }
#pragma unroll
    for (int ks = 0; ks < 2; ++ks) {
      short8 af  = *(const short8*)(Abuf + aoff  + ks * 64);
      short8 bf0 = *(const short8*)(Bbuf + boff0 + ks * 64);
      short8 bf1 = *(const short8*)(Bbuf + boff1 + ks * 64);
      acc0 = __builtin_amdgcn_mfma_f32_16x16x32_bf16(af, bf0, acc0, 0, 0, 0);
      acc1 = __builtin_amdgcn_mfma_f32_16x16x32_bf16(af, bf1, acc1, 0, 0, 0);
    }
  }

  // epilogue: C layout col=lane&15, row=(lane>>4)*4+i
#pragma unroll
  for (int nf = 0; nf < 2; ++nf) {
    const f32x4 a = nf ? acc1 : acc0;
    const int col = n0 + n0w + nf * 16 + lr;
    const float bv = bias[col];
#pragma unroll
    for (int i = 0; i < 4; ++i) {
      const int mrow = m0 + r0 + lg * 4 + i;
      const float val = exp2f((a[i] + bv) * EXP2K);
      if (!second) {
        E1[(size_t)mrow * DD + col] = val;
      } else {
        const int m2 = mrow - BB * LL;
        E2c[((size_t)(col >> 2) * (BB * TT) + m2) * 4 + (col & 3)] = val;
      }
    }
  }
}

// ---------------------------------------------------------------------------
// Kernel 2: score + softmax (R20/R22/R24-proven). 512 threads, 8 waves x
// d-octant; zero barriers in the tile loop; one combined cross-octant
// reduce; S fully initialized; normalized f32 P store. Anti-diagonal tile
// sharing (tc >= tc1: one vv load feeds both rows). XCD-affinity decode.
// ---------------------------------------------------------------------------
__global__ __launch_bounds__(512) void score_softmax(
    const float* __restrict__ E1, const float* __restrict__ E2c,
    const float* __restrict__ wt, const int* __restrict__ mask,
    float* __restrict__ Pg)
{
  __shared__ float prt[2][4][8][64];       // (row, tile, d-octant, t-lane) 16KB
  __shared__ float S[2][TT];               // raw scores per row             2KB

  const int tid = threadIdx.x;             // 0..511
  const int tl  = tid & 63;
  const int wv  = tid >> 6;                // 0..7
  const int dq  = __builtin_amdgcn_readfirstlane(wv);  // wave-uniform octant

  // XCD-affinity decode (bid%8 = XCD round-robin)
  const int bid = blockIdx.x;              // 0..511
  const int k   = bid & 7;
  const int b   = k >> 1;
  const int lp  = (bid >> 3) + ((k & 1) << 6);   // 0..127

  const int r0 = lp;
  const int r1 = 255 - lp;
  const int tc0 = r0 >> 6;          // 0 or 1
  const int tc1 = r1 >> 6;          // 3 or 2  (tc1 == 3 - tc0)

  const size_t strE2 = (size_t)(BB * TT);  // float4 stride per d4 plane
  const float4* wp  = (const float4*)wt + dq * 16;
  const float4* q0p = (const float4*)(E1 + (size_t)(b * LL + r0) * DD) + dq * 16;
  const float4* q1p = (const float4*)(E1 + (size_t)(b * LL + r1) * DD) + dq * 16;

  // ---- score phase: loop over tiles, NO barriers inside ----
  for (int tc = tc0; tc < 4; ++tc) {
    const bool shr = (tc >= tc1);          // block-uniform
    const int t = tc * 64 + tl;
    const float4* vp = (const float4*)E2c + (size_t)(dq * 16) * strE2 + (b * TT + t);

    float a0 = 0.f, a1 = 0.f, a2 = 0.f, a3 = 0.f;
    float b0 = 0.f, b1 = 0.f, b2 = 0.f, b3 = 0.f;
    if (shr) {
#pragma unroll 8
      for (int j = 0; j < 16; ++j) {
        float4 vv = vp[(size_t)j * strE2];
        float4 q0 = q0p[j];
        float4 q1 = q1p[j];
        float4 w  = wp[j];
        a0 = fmaf(w.x, __builtin_amdgcn_rcpf(fmaf(q0.x, vv.x, 1.0f)), a0);
        a1 = fmaf(w.y, __builtin_amdgcn_rcpf(fmaf(q0.y, vv.y, 1.0f)), a1);
        a2 = fmaf(w.z, __builtin_amdgcn_rcpf(fmaf(q0.z, vv.z, 1.0f)), a2);
        a3 = fmaf(w.w, __builtin_amdgcn_rcpf(fmaf(q0.w, vv.w, 1.0f)), a3);
        b0 = fmaf(w.x, __builtin_amdgcn_rcpf(fmaf(q1.x, vv.x, 1.0f)), b0);
        b1 = fmaf(w.y, __builtin_amdgcn_rcpf(fmaf(q1.y, vv.y, 1.0f)), b1);
        b2 = fmaf(w.z, __builtin_amdgcn_rcpf(fmaf(q1.z, vv.z, 1.0f)), b2);
        b3 = fmaf(w.w, __builtin_amdgcn_rcpf(fmaf(q1.w, vv.w, 1.0f)), b3);
      }
    } else {
#pragma unroll 8
      for (int j = 0; j < 16; ++j) {
        float4 vv = vp[(size_t)j * strE2];
        float4 q0 = q0p[j];
        float4 w  = wp[j];
        a0 = fmaf(w.x, __builtin_amdgcn_rcpf(fmaf(q0.x, vv.x, 1.0f)), a0);
        a1 = fmaf(w.y, __builtin_amdgcn_rcpf(fmaf(q0.y, vv.y, 1.0f)), a1);
        a2 = fmaf(w.z, __builtin_amdgcn_rcpf(fmaf(q0.z, vv.z, 1.0f)), a2);
        a3 = fmaf(w.w, __builtin_amdgcn_rcpf(fmaf(q0.w, vv.w, 1.0f)), a3);
      }
    }
    prt[0][tc][dq][tl] = (a0 + a1) + (a2 + a3);
    if (shr) prt[1][tc][dq][tl] = (b0 + b1) + (b2 + b3);
  }
  __syncthreads();

  // ---- single cross-octant reduce: 512 threads; S fully initialized ----
  {
    const int rr = tid >> 8;           // 0..1
    const int t  = tid & 255;
    const int lo = (rr ? tc1 : tc0) << 6;
    if (t >= lo) {
      const float* pp = &prt[rr][t >> 6][0][t & 63];
      float s = 0.f;
#pragma unroll
      for (int oc = 0; oc < 8; ++oc) s += pp[oc * 64];
      S[rr][t] = s;
    } else {
      S[rr][t] = 5e29f;               // -2*S = -1e30 (masked sentinel)
    }
  }
  __syncthreads();

  // ---- softmax + normalized f32 P store: wave 0 -> r0, wave 1 -> r1 ----
  if (wv < 2) {
    const int row = wv ? r1 : r0;
    const int tb = tl * 4;
    float4 h = *(const float4*)(&S[wv][tb]);
    const int4 mk = *(const int4*)(mask + b * TT + tb);
    float v0 = (tb + 0 >= row && mk.x != 0) ? -2.0f * h.x : -1e30f;
    float v1 = (tb + 1 >= row && mk.y != 0) ? -2.0f * h.y : -1e30f;
    float v2 = (tb + 2 >= row && mk.z != 0) ? -2.0f * h.z : -1e30f;
    float v3 = (tb + 3 >= row && mk.w != 0) ? -2.0f * h.w : -1e30f;
    float mx = fmaxf(fmaxf(v0, v1), fmaxf(v2, v3));
#pragma unroll
    for (int o = 1; o < 64; o <<= 1) mx = fmaxf(mx, __shfl_xor(mx, o));
    float e0 = __expf(v0 - mx), e1 = __expf(v1 - mx),
          e2 = __expf(v2 - mx), e3 = __expf(v3 - mx);
    float sm = (e0 + e1) + (e2 + e3);
#pragma unroll
    for (int o = 1; o < 64; o <<= 1) sm += __shfl_xor(sm, o);
    const float rinv = 1.0f / sm;            // butterfly: all lanes have sum
    float4 pv = {e0 * rinv, e1 * rinv, e2 * rinv, e3 * rinv};
    *(float4*)(Pg + (size_t)(b * LL + row) * TT + tb) = pv;
  }
}

// ---------------------------------------------------------------------------
// Kernel 3: PV as bf16-MFMA GEMM with register-prefetch staging (R22-proven,
// unchanged). out[b] = P[b] (MxK) x mem[b] (KxN), 32x64 tile, BK=64,
// 256 threads. A = Pg (f32) cvt'd to bf16 at LDS-write. B = mem staged with
// in-LDS transpose. fp32 accumulate, direct f32 store.
// ---------------------------------------------------------------------------
__global__ __launch_bounds__(256) void pv_gemm(
    const float* __restrict__ Pg, const float* __restrict__ mem,
    float* __restrict__ out)
{
  __shared__ __align__(16) char Abuf[32 * 144];   // 32 rows x 64 bf16 (+pad)
  __shared__ __align__(16) char Bbuf[64 * 144];   // 64 n-cols x 64 k bf16 (+pad)

  const int tid = threadIdx.x;
  const int bid = blockIdx.x;          // 0..255
  const int b   = bid >> 6;
  const int rem = bid & 63;
  const int m0  = (rem >> 3) * 32;
  const int n0  = (rem & 7) * 64;

  const int arow = tid >> 3;           // 0..31
  const int k8   = (tid & 7) * 8;      // 0..56
  const int nq   = tid & 15;           // n quad 0..15
  const int kp0  = tid >> 4;           // k-pair 0..15 (and +16)

  const int lane = tid & 63;
  const int wid  = tid >> 6;
  const int r0   = (wid & 1) * 16;
  const int n0w  = (wid >> 1) * 32;
  const int lr   = lane & 15;
  const int lg   = lane >> 4;

  const int aoff  = (r0 + lr) * 144 + lg * 16;
  const int boff0 = (n0w + lr) * 144 + lg * 16;
  const int boff1 = (n0w + 16 + lr) * 144 + lg * 16;

  f32x4 acc0 = {0.f, 0.f, 0.f, 0.f};
  f32x4 acc1 = {0.f, 0.f, 0.f, 0.f};

  const float* Pb = Pg + (size_t)(b * LL) * TT;
  const float* Mb = mem + (size_t)(b * TT) * DD;
  const float* Pa = Pb + (size_t)(m0 + arow) * TT + k8;
  const float* Mq = Mb + n0 + nq * 4;

  // preload tile kc=0
  float4 pa1 = *(const float4*)(Pa);
  float4 pa2 = *(const float4*)(Pa + 4);
  float4 fa0 = *(const float4*)(Mq + (size_t)(kp0 * 2) * DD);
  float4 fb0 = *(const float4*)(Mq + (size_t)(kp0 * 2 + 1) * DD);
  float4 fa1 = *(const float4*)(Mq + (size_t)((kp0 + 16) * 2) * DD);
  float4 fb1 = *(const float4*)(Mq + (size_t)((kp0 + 16) * 2 + 1) * DD);

  for (int kc = 0; kc < TT; kc += 64) {
    __syncthreads();
    // A: P tile — cvt at write time
    {
      uint4 u = {cvt2bf(pa1.x, pa1.y), cvt2bf(pa1.z, pa1.w),
                 cvt2bf(pa2.x, pa2.y), cvt2bf(pa2.z, pa2.w)};
      *(uint4*)(Abuf + arow * 144 + k8 * 2) = u;
    }
    // B: mem tile transpose-write
    {
      *(unsigned*)(Bbuf + (nq * 4 + 0) * 144 + kp0 * 4) = cvt2bf(fa0.x, fb0.x);
      *(unsigned*)(Bbuf + (nq * 4 + 1) * 144 + kp0 * 4) = cvt2bf(fa0.y, fb0.y);
      *(unsigned*)(Bbuf + (nq * 4 + 2) * 144 + kp0 * 4) = cvt2bf(fa0.z, fb0.z);
      *(unsigned*)(Bbuf + (nq * 4 + 3) * 144 + kp0 * 4) = cvt2bf(fa0.w, fb0.w);
      const int kp1 = kp0 + 16;
      *(unsigned*)(Bbuf + (nq * 4 + 0) * 144 + kp1 * 4) = cvt2bf(fa1.x, fb1.x);
      *(unsigned*)(Bbuf + (nq * 4 + 1) * 144 + kp1 * 4) = cvt2bf(fa1.y, fb1.y);
      *(unsigned*)(Bbuf + (nq * 4 + 2) * 144 + kp1 * 4) = cvt2bf(fa1.z, fb1.z);
      *(unsigned*)(Bbuf + (nq * 4 + 3) * 144 + kp1 * 4) = cvt2bf(fa1.w, fb1.w);
    }
    __syncthreads();
    if (kc + 64 < TT) {   // prefetch next tile; retires under MFMA
      const int kn = kc + 64;
      pa1 = *(const float4*)(Pa + kn);
      pa2 = *(const float4*)(Pa + kn + 4);
      fa0 = *(const float4*)(Mq + (size_t)(kn + kp0 * 2) * DD);
      fb0 = *(const float4*)(Mq + (size_t)(kn + kp0 * 2 + 1) * DD);
      fa1 = *(const float4*)(Mq + (size_t)(kn + (kp0 + 16) * 2) * DD);
      fb1 = *(const float4*)(Mq + (size_t)(kn + (kp0 + 16) * 2 + 1) * DD);
    }
#pragma unroll
    for (int ks = 0; ks < 2; ++ks) {
      short8 af  = *(const short8*)(Abuf + aoff  + ks * 64);
      short8 bf0 = *(const short8*)(Bbuf + boff0 + ks * 64);
      short8 bf1 = *(const short8*)(Bbuf + boff1 + ks * 64);
      acc0 = __builtin_amdgcn_mfma_f32_16x16x32_bf16(af, bf0, acc0, 0, 0, 0);
      acc1 = __builtin_amdgcn_mfma_f32_16x16x32_bf16(af, bf1, acc1, 0, 0, 0);
    }
  }

  // epilogue: direct f32 store (no bias/activation)
#pragma unroll
  for (int nf = 0; nf < 2; ++nf) {
    const f32x4 a = nf ? acc1 : acc0;
    const int col = n0 + n0w + nf * 16 + lr;
#pragma unroll
    for (int i = 0; i < 4; ++i) {
      const int mrow = m0 + r0 + lg * 4 + i;
      out[(size_t)(b * LL + mrow) * DD + col] = a[i];
    }
  }
}

extern "C" void kernel_launch(void* const* d_in, const int* in_sizes, int n_in,
                              void* d_out, int out_size, void* d_ws, size_t ws_size,
                              hipStream_t stream) {
  const float* x   = (const float*)d_in[0];
  const float* mem = (const float*)d_in[1];
  const float* W1  = (const float*)d_in[2];
  const float* b1  = (const float*)d_in[3];
  const float* W2  = (const float*)d_in[4];
  const float* b2  = (const float*)d_in[5];
  const float* wt  = (const float*)d_in[6];
  const int* mask  = (const int*)d_in[8];
  float* outp = (float*)d_out;

  float* E1  = (float*)d_ws;                     // [B*L, D]      2 MB f32
  float* E2c = E1 + (size_t)BB * LL * DD;        // chunked       2 MB f32
  float* Pg  = E2c + (size_t)BB * TT * DD;       // [B][L][T]     1 MB f32 (5 MB)

  proj_gemm<<<dim3((BB * LL + BB * TT) / 32, DD / 64), 256, 0, stream>>>(
      x, mem, W1, b1, W2, b2, E1, E2c);
  score_softmax<<<512, 512, 0, stream>>>(E1, E2c, wt, mask, Pg);
  pv_gemm<<<256, 256, 0, stream>>>(Pg, mem, outp);
}